// Round 1
// 147.635 us; speedup vs baseline: 1.0404x; 1.0404x over previous
//
#include <hip/hip_runtime.h>
#include <stdint.h>

#define TWF 0.2f
#define NPTS 16384

typedef __attribute__((ext_vector_type(8))) short short8;
typedef __attribute__((ext_vector_type(4))) float floatx4;

__device__ __forceinline__ short f2bf(float f){
  unsigned u = __float_as_uint(f);
  u += 0x7fff + ((u >> 16) & 1);           // round-to-nearest-even
  return (short)(u >> 16);
}
__device__ __forceinline__ float bf2f(short s){
  return __uint_as_float(((unsigned)(unsigned short)s) << 16);
}
// tanh(x) = 1 - 2/(exp2(2*log2e*x)+1); exact at +/-inf
__device__ __forceinline__ float fast_tanh(float x){
  float e = __builtin_amdgcn_exp2f(x * 2.885390082f);
  float r = __builtin_amdgcn_rcpf(e + 1.f);
  return fmaf(-2.f, r, 1.f);
}
// cos(pi*t) via v_cos (revolutions)
__device__ __forceinline__ float cospi_t(float t){
  return __builtin_amdgcn_cosf(t * 0.5f);
}
// packed f32x2 -> bf16x2 (RTNE in HW); low 16 = lo, high 16 = hi
__device__ __forceinline__ unsigned cvt_pk_bf16(float lo, float hi){
  unsigned r;
  asm("v_cvt_pk_bf16_f32 %0, %1, %2" : "=v"(r) : "v"(lo), "v"(hi));
  return r;
}

// ws layout (bytes):
//   [0, 4M)            : bf16-swizzled W1/W2
//   [4M, 4M+4K)        : counts[16], 128B stride (one L2 line each)
//   [4M+4K, 5M+4K)     : ilist[16][16384]
//   [5M+4K, 6M+4K)     : wlist[16][16384]
#define WS_W      0
#define WS_CNT    (4u<<20)
#define WS_ILIST  ((4u<<20) + 4096u)
#define WS_WLIST  ((5u<<20) + 4096u)
#define CNT(k)    counts[(k) * 32]

// Fused: blocks [0,1024) convert W1/W2 to bf16 fragment order;
// blocks [1024,1088) zero `out` and build per-k compacted point lists
// (block-aggregated atomics: 1 atomicAdd per block per k, padded lines).
__global__ __launch_bounds__(256) void prep_fused(
    const float* __restrict__ W1, const float* __restrict__ W2,
    const float* __restrict__ x,  const float* __restrict__ xmins,
    const float* __restrict__ xmaxs, short* __restrict__ dst,
    int* __restrict__ counts, int* __restrict__ ilist, float* __restrict__ wlist,
    float* __restrict__ out){
  if (blockIdx.x < 1024){
    int gid = blockIdx.x * 256 + threadIdx.x;   // 2*16*8*16*64 = 262144 total
    int lane = gid & 63; int rest = gid >> 6;
    int jt = rest & 15; rest >>= 4;
    int ks = rest & 7;  rest >>= 3;
    int k  = rest & 15; int mat = rest >> 4;
    const float* W = mat ? W2 : W1;
    int j   = jt * 16 + (lane & 15);
    int kk0 = ks * 32 + (lane >> 4) * 8;
    short8 v;
    #pragma unroll
    for (int jj = 0; jj < 8; jj++)
      v[jj] = f2bf(W[k * 65536 + (kk0 + jj) * 256 + j]);
    *(short8*)(dst + (size_t)gid * 8) = v;
  } else {
    __shared__ int s_wcnt[4];
    __shared__ int s_base;
    int gid  = (blockIdx.x - 1024) * 256 + threadIdx.x;  // one thread per point
    int t    = threadIdx.x;
    int lane = t & 63, wave = t >> 6;
    out[gid] = 0.f;                                      // fold memset(out)
    float px = x[gid * 2 + 0], py = x[gid * 2 + 1];
    float wr[16]; float sum = 0.f;
    #pragma unroll
    for (int k = 0; k < 16; k++){
      float w = 1.f;
      #pragma unroll
      for (int d = 0; d < 2; d++){
        float xv = d ? py : px;
        float mn = xmins[k * 2 + d], mx = xmaxs[k * 2 + d];
        float tl = fminf(fmaxf((xv - (mn - TWF)) * (1.f / (2.f * TWF)), 0.f), 1.f);
        float tr = fminf(fmaxf(((mx + TWF) - xv) * (1.f / (2.f * TWF)), 0.f), 1.f);
        w *= 0.25f * (1.f - cospi_t(tl)) * (1.f - cospi_t(tr));
      }
      wr[k] = w; sum += w;
    }
    float inv = 1.f / (sum + 1e-9f);
    #pragma unroll 1
    for (int kk = 0; kk < 16; kk++){
      int k = (kk + blockIdx.x) & 15;              // spread initial line load
      bool act = wr[k] > 0.f;
      unsigned long long mask = __ballot(act);
      if (lane == 0) s_wcnt[wave] = (int)__popcll(mask);
      __syncthreads();
      int tot = s_wcnt[0] + s_wcnt[1] + s_wcnt[2] + s_wcnt[3];
      int wpre = 0;
      #pragma unroll
      for (int w = 0; w < 4; w++) wpre += (w < wave) ? s_wcnt[w] : 0;
      if (t == 0) s_base = atomicAdd(&CNT(k), tot);
      __syncthreads();
      if (act){
        int pos = s_base + wpre + (int)__popcll(mask & ((1ull << lane) - 1ull));
        ilist[k * NPTS + pos] = gid;
        wlist[k * NPTS + pos] = wr[k] * inv;
      }
    }
  }
}

// Packed tanh+bf16 writeback: acc[rt][ct] holds D[j'][m] with
// j' = (wave*4+rt)*16 + quad*4 + r (4 CONSECUTIVE rows) and m = ct*16+col.
// One cvt_pk pair + one 8B ds_write per 4 elements, into the chunk-XOR
// swizzled [m][j] layout (same layout the B-frag reads & layer3 expect).
__device__ __forceinline__ void store_h_packed(
    short* lds_h, const floatx4 (&acc)[4][4], const floatx4 (&bb)[4],
    int wave, int quad, int col){
  #pragma unroll
  for (int rt = 0; rt < 4; rt++){
    const int j0    = (wave * 4 + rt) * 16 + quad * 4;
    const int cbase = j0 >> 3;
    const int off   = j0 & 7;                 // 0 or 4 within the 8-short chunk
    #pragma unroll
    for (int ct = 0; ct < 4; ct++){
      const int m = ct * 16 + col;
      float t0 = fast_tanh(acc[rt][ct][0] + bb[rt][0]);
      float t1 = fast_tanh(acc[rt][ct][1] + bb[rt][1]);
      float t2 = fast_tanh(acc[rt][ct][2] + bb[rt][2]);
      float t3 = fast_tanh(acc[rt][ct][3] + bb[rt][3]);
      uint2 v = make_uint2(cvt_pk_bf16(t0, t1), cvt_pk_bf16(t2, t3));
      *(uint2*)&lds_h[m * 256 + ((cbase ^ (m & 7)) << 3) + off] = v;
    }
  }
}

__global__ __launch_bounds__(256, 4) void fbpinn_main(
    const float* __restrict__ x,  const float* __restrict__ W0, const float* __restrict__ b0,
    const float* __restrict__ b1, const float* __restrict__ b2,
    const float* __restrict__ W3, const float* __restrict__ b3,
    const float* __restrict__ xmins, const float* __restrict__ xmaxs,
    const short* __restrict__ wsw, const int* __restrict__ counts,
    const int* __restrict__ ilist, const float* __restrict__ wlist,
    float* __restrict__ out)
{
  __shared__ short lds_h[64 * 256];   // 32 KB, swizzled bf16 h tile, [m][j]
  __shared__ float s_xn[64 * 2];
  __shared__ float s_win[64];
  __shared__ int   s_pidx[64];
  __shared__ float s_w3[256];
  __shared__ float s_w0[512];

  const int t    = threadIdx.x;
  const int lane = t & 63;
  const int wave = t >> 6;
  const int col  = lane & 15;
  const int quad = lane >> 4;

  // live-tile partition: prefix over per-k tile counts
  int tb[17]; tb[0] = 0;
  #pragma unroll
  for (int kk = 0; kk < 16; kk++) tb[kk + 1] = tb[kk] + ((CNT(kk) + 63) >> 6);
  const int total = tb[16];

  for (int tile = blockIdx.x; tile < total; tile += gridDim.x){
    int k = 0;
    #pragma unroll
    for (int kk = 1; kk < 16; kk++) k += (tile >= tb[kk]);
    const int base = (tile - tb[k]) * 64;
    const int cnt  = CNT(k);

    __syncthreads();   // previous tile's layer-3 reads done before s_* overwrite

    // ---- stage: gather compacted points, normalize, stage W0/W3 ----
    s_w3[t] = W3[k * 256 + t];
    s_w0[t] = W0[k * 512 + t];
    s_w0[256 + t] = W0[k * 512 + 256 + t];
    if (t < 64){
      int gi = base + t;
      bool valid = gi < cnt;
      int pidx = valid ? ilist[k * NPTS + gi] : 0;
      float w  = valid ? wlist[k * NPTS + gi] : 0.f;
      s_pidx[t] = pidx;
      s_win[t]  = w;
      float px = x[pidx * 2 + 0], py = x[pidx * 2 + 1];
      float cx = (xmins[k * 2 + 0] + xmaxs[k * 2 + 0]) * 0.5f;
      float cy = (xmins[k * 2 + 1] + xmaxs[k * 2 + 1]) * 0.5f;
      float sx = fmaxf((xmaxs[k * 2 + 0] - xmins[k * 2 + 0]) * 0.5f, 1e-9f);
      float sy = fmaxf((xmaxs[k * 2 + 1] - xmins[k * 2 + 1]) * 0.5f, 1e-9f);
      s_xn[t * 2 + 0] = (px - cx) / sx;
      s_xn[t * 2 + 1] = (py - cy) / sy;
    }
    __syncthreads();

    // ---- layer 0 (D=2 -> 256), swapped roles: D[j'][m] = W0^T(j',d) * xn^T(d,m) ----
    {
      short8 wfr[4], xfr[4];
      #pragma unroll
      for (int rt = 0; rt < 4; rt++){
        int j = (wave * 4 + rt) * 16 + col;        // A row = out-feature j'
        short8 a;
        #pragma unroll
        for (int i = 0; i < 8; i++) a[i] = 0;
        a[0] = (quad == 0) ? f2bf(s_w0[j])       : (short)0;
        a[1] = (quad == 0) ? f2bf(s_w0[256 + j]) : (short)0;
        wfr[rt] = a;
      }
      #pragma unroll
      for (int ct = 0; ct < 4; ct++){
        int m = ct * 16 + col;                     // B col = point m
        short8 b;
        #pragma unroll
        for (int i = 0; i < 8; i++) b[i] = 0;
        b[0] = (quad == 0) ? f2bf(s_xn[m * 2 + 0]) : (short)0;
        b[1] = (quad == 0) ? f2bf(s_xn[m * 2 + 1]) : (short)0;
        xfr[ct] = b;
      }
      floatx4 bb[4];
      #pragma unroll
      for (int rt = 0; rt < 4; rt++)
        bb[rt] = *(const floatx4*)&b0[k * 256 + (wave * 4 + rt) * 16 + quad * 4];
      floatx4 acc[4][4];
      #pragma unroll
      for (int a = 0; a < 4; a++)
        #pragma unroll
        for (int b = 0; b < 4; b++)
          acc[a][b] = (floatx4){0.f, 0.f, 0.f, 0.f};
      #pragma unroll
      for (int rt = 0; rt < 4; rt++)
        #pragma unroll
        for (int ct = 0; ct < 4; ct++)
          acc[rt][ct] = __builtin_amdgcn_mfma_f32_16x16x32_bf16(wfr[rt], xfr[ct], acc[rt][ct], 0, 0, 0);
      store_h_packed(lds_h, acc, bb, wave, quad, col);
      __syncthreads();
    }

    // ---- layers 1,2: D[j'][m] = W^T * h^T; weights = A (global), h = B (LDS) ----
    #pragma unroll 1
    for (int layer = 0; layer < 2; layer++){
      const short8* wb = (const short8*)(wsw + (size_t)layer * 1048576)
                         + ((size_t)(k * 8) * 16 + wave * 4) * 64 + lane;
      const float*  bp = layer ? b2 : b1;
      floatx4 bb[4];
      #pragma unroll
      for (int rt = 0; rt < 4; rt++)
        bb[rt] = *(const floatx4*)&bp[k * 256 + (wave * 4 + rt) * 16 + quad * 4];
      floatx4 acc[4][4];
      #pragma unroll
      for (int a = 0; a < 4; a++)
        #pragma unroll
        for (int b = 0; b < 4; b++)
          acc[a][b] = (floatx4){0.f, 0.f, 0.f, 0.f};

      short8 wcur[4];
      #pragma unroll
      for (int rt = 0; rt < 4; rt++) wcur[rt] = wb[rt * 64];

      #pragma unroll
      for (int ks = 0; ks < 8; ks++){
        short8 wnxt[4];
        if (ks < 7){
          #pragma unroll
          for (int rt = 0; rt < 4; rt++)
            wnxt[rt] = wb[(ks + 1) * 1024 + rt * 64];   // prefetch next K-step
        }
        short8 hfr[4];
        #pragma unroll
        for (int ct = 0; ct < 4; ct++){
          int m   = ct * 16 + col;                 // B: col = point m
          int pos = (ks * 4 + quad) ^ (m & 7);     // B: k-chunk = quad
          hfr[ct] = *(const short8*)&lds_h[m * 256 + pos * 8];
        }
        #pragma unroll
        for (int rt = 0; rt < 4; rt++)
          #pragma unroll
          for (int ct = 0; ct < 4; ct++)
            acc[rt][ct] = __builtin_amdgcn_mfma_f32_16x16x32_bf16(wcur[rt], hfr[ct], acc[rt][ct], 0, 0, 0);
        if (ks < 7){
          #pragma unroll
          for (int rt = 0; rt < 4; rt++) wcur[rt] = wnxt[rt];
        }
      }
      __syncthreads();   // all reads of h done before overwrite

      store_h_packed(lds_h, acc, bb, wave, quad, col);
      __syncthreads();
    }

    // ---- layer 3 (256 -> 1) + window-weighted scatter ----
    {
      int m = t >> 2, q = t & 3;     // 4 threads per point
      float dot = 0.f;
      #pragma unroll
      for (int cc = 0; cc < 8; cc++){
        int ci  = q * 8 + cc;
        int pos = ci ^ (m & 7);
        short8 hv = *(const short8*)&lds_h[m * 256 + pos * 8];
        #pragma unroll
        for (int jj = 0; jj < 8; jj++)
          dot = fmaf(bf2f(hv[jj]), s_w3[ci * 8 + jj], dot);
      }
      dot += __shfl_xor(dot, 1);
      dot += __shfl_xor(dot, 2);
      if (q == 0 && s_win[m] != 0.f)
        atomicAdd(&out[s_pidx[m]], s_win[m] * (dot + b3[k]));
    }
  }
}

extern "C" void kernel_launch(void* const* d_in, const int* in_sizes, int n_in,
                              void* d_out, int out_size, void* d_ws, size_t ws_size,
                              hipStream_t stream){
  const float* x     = (const float*)d_in[0];
  const float* W0    = (const float*)d_in[1];
  const float* b0    = (const float*)d_in[2];
  const float* W1    = (const float*)d_in[3];
  const float* b1    = (const float*)d_in[4];
  const float* W2    = (const float*)d_in[5];
  const float* b2    = (const float*)d_in[6];
  const float* W3    = (const float*)d_in[7];
  const float* b3    = (const float*)d_in[8];
  const float* xmins = (const float*)d_in[9];
  const float* xmaxs = (const float*)d_in[10];
  float* out = (float*)d_out;

  char* ws = (char*)d_ws;                     // needs ~6.3 MB
  short* wsw   = (short*)(ws + WS_W);
  int*   cnts  = (int*)  (ws + WS_CNT);
  int*   ilist = (int*)  (ws + WS_ILIST);
  float* wlist = (float*)(ws + WS_WLIST);

  (void)hipMemsetAsync(cnts, 0, 4096, stream);
  prep_fused<<<1024 + NPTS / 256, 256, 0, stream>>>(W1, W2, x, xmins, xmaxs,
                                                    wsw, cnts, ilist, wlist, out);
  // grid 2048: tile count (~1250, data-dependent) < grid, so each tile gets its
  // own block -> 1 tile/block, 4 blocks/CU resident (LDS 36.9KB caps at 4),
  // natural tail load-balancing. Surplus blocks exit after the prefix scan.
  fbpinn_main<<<2048, 256, 0, stream>>>(x, W0, b0, b1, b2, W3, b3, xmins, xmaxs,
                                        wsw, cnts, ilist, wlist, out);
}

// Round 3
// 139.055 us; speedup vs baseline: 1.1046x; 1.0617x over previous
//
#include <hip/hip_runtime.h>
#include <stdint.h>

#define TWF 0.2f
#define NPTS 16384

typedef __attribute__((ext_vector_type(8))) short short8;
typedef __attribute__((ext_vector_type(4))) float floatx4;

__device__ __forceinline__ short f2bf(float f){
  unsigned u = __float_as_uint(f);
  u += 0x7fff + ((u >> 16) & 1);           // round-to-nearest-even
  return (short)(u >> 16);
}
__device__ __forceinline__ float bf2f(short s){
  return __uint_as_float(((unsigned)(unsigned short)s) << 16);
}
// tanh(x) = 1 - 2/(exp2(2*log2e*x)+1); exact at +/-inf
__device__ __forceinline__ float fast_tanh(float x){
  float e = __builtin_amdgcn_exp2f(x * 2.885390082f);
  float r = __builtin_amdgcn_rcpf(e + 1.f);
  return fmaf(-2.f, r, 1.f);
}
// cos(pi*t) via v_cos (revolutions)
__device__ __forceinline__ float cospi_t(float t){
  return __builtin_amdgcn_cosf(t * 0.5f);
}
// packed f32x2 -> bf16x2 (RTNE in HW); low 16 = lo, high 16 = hi
__device__ __forceinline__ unsigned cvt_pk_bf16(float lo, float hi){
  unsigned r;
  asm("v_cvt_pk_bf16_f32 %0, %1, %2" : "=v"(r) : "v"(lo), "v"(hi));
  return r;
}

// ws layout (bytes):
//   [0, 4M)            : bf16-swizzled W1/W2
//   [4M, 4M+4K)        : counts[16], 128B stride (one L2 line each)
//   [4M+4K, 5M+4K)     : ilist[16][16384]
//   [5M+4K, 6M+4K)     : wlist[16][16384]
#define WS_W      0
#define WS_CNT    (4u<<20)
#define WS_ILIST  ((4u<<20) + 4096u)
#define WS_WLIST  ((5u<<20) + 4096u)
#define CNT(k)    counts[(k) * 32]

// Fused: blocks [0,1024) convert W1/W2 to bf16 fragment order;
// blocks [1024,1280) zero `out` and build per-k compacted point lists.
// List-building split 4-way over k (vs 16-k serial loop in one block):
// 256 blocks -> 4x the CUs, 4x shorter serial atomic-round-trip chain.
__global__ __launch_bounds__(256) void prep_fused(
    const float* __restrict__ W1, const float* __restrict__ W2,
    const float* __restrict__ x,  const float* __restrict__ xmins,
    const float* __restrict__ xmaxs, short* __restrict__ dst,
    int* __restrict__ counts, int* __restrict__ ilist, float* __restrict__ wlist,
    float* __restrict__ out){
  if (blockIdx.x < 1024){
    int gid = blockIdx.x * 256 + threadIdx.x;   // 2*16*8*16*64 = 262144 total
    int lane = gid & 63; int rest = gid >> 6;
    int jt = rest & 15; rest >>= 4;
    int ks = rest & 7;  rest >>= 3;
    int k  = rest & 15; int mat = rest >> 4;
    const float* W = mat ? W2 : W1;
    int j   = jt * 16 + (lane & 15);
    int kk0 = ks * 32 + (lane >> 4) * 8;
    short8 v;
    #pragma unroll
    for (int jj = 0; jj < 8; jj++)
      v[jj] = f2bf(W[k * 65536 + (kk0 + jj) * 256 + j]);
    *(short8*)(dst + (size_t)gid * 8) = v;
  } else {
    __shared__ int s_wcnt[4];
    __shared__ int s_base;
    int b2    = blockIdx.x - 1024;               // [0,256)
    int g     = b2 & 3;                          // k-group: handles k in [g*4, g*4+4)
    int chunk = b2 >> 2;                         // point chunk [0,64)
    int t     = threadIdx.x;
    int gid   = chunk * 256 + t;                 // one thread per point (per group)
    int lane  = t & 63, wave = t >> 6;
    if (g == 0) out[gid] = 0.f;                  // fold memset(out), once
    float px = x[gid * 2 + 0], py = x[gid * 2 + 1];
    float wr[16]; float sum = 0.f;               // need all 16 for the sum
    #pragma unroll
    for (int k = 0; k < 16; k++){
      float w = 1.f;
      #pragma unroll
      for (int d = 0; d < 2; d++){
        float xv = d ? py : px;
        float mn = xmins[k * 2 + d], mx = xmaxs[k * 2 + d];
        float tl = fminf(fmaxf((xv - (mn - TWF)) * (1.f / (2.f * TWF)), 0.f), 1.f);
        float tr = fminf(fmaxf(((mx + TWF) - xv) * (1.f / (2.f * TWF)), 0.f), 1.f);
        w *= 0.25f * (1.f - cospi_t(tl)) * (1.f - cospi_t(tr));
      }
      wr[k] = w; sum += w;
    }
    float inv = 1.f / (sum + 1e-9f);
    #pragma unroll 1
    for (int kk = 0; kk < 4; kk++){
      int k = g * 4 + ((kk + chunk) & 3);        // stagger initial line load
      bool act = wr[k] > 0.f;
      unsigned long long mask = __ballot(act);
      if (lane == 0) s_wcnt[wave] = (int)__popcll(mask);
      __syncthreads();
      int tot = s_wcnt[0] + s_wcnt[1] + s_wcnt[2] + s_wcnt[3];
      int wpre = 0;
      #pragma unroll
      for (int w = 0; w < 4; w++) wpre += (w < wave) ? s_wcnt[w] : 0;
      if (t == 0) s_base = atomicAdd(&CNT(k), tot);
      __syncthreads();
      if (act){
        int pos = s_base + wpre + (int)__popcll(mask & ((1ull << lane) - 1ull));
        ilist[k * NPTS + pos] = gid;
        wlist[k * NPTS + pos] = wr[k] * inv;
      }
    }
  }
}

// Packed tanh+bf16 writeback: acc[rt][ct] holds D[j'][m] with
// j' = (wave*4+rt)*16 + quad*4 + r (4 CONSECUTIVE rows) and m = ct*16+col.
// One cvt_pk pair + one 8B ds_write per 4 elements, into the chunk-XOR
// swizzled [m][j] layout (same layout the B-frag reads & layer3 expect).
__device__ __forceinline__ void store_h_packed(
    short* lds_h, const floatx4 (&acc)[4][4], const floatx4 (&bb)[4],
    int wave, int quad, int col){
  #pragma unroll
  for (int rt = 0; rt < 4; rt++){
    const int j0    = (wave * 4 + rt) * 16 + quad * 4;
    const int cbase = j0 >> 3;
    const int off   = j0 & 7;                 // 0 or 4 within the 8-short chunk
    #pragma unroll
    for (int ct = 0; ct < 4; ct++){
      const int m = ct * 16 + col;
      float t0 = fast_tanh(acc[rt][ct][0] + bb[rt][0]);
      float t1 = fast_tanh(acc[rt][ct][1] + bb[rt][1]);
      float t2 = fast_tanh(acc[rt][ct][2] + bb[rt][2]);
      float t3 = fast_tanh(acc[rt][ct][3] + bb[rt][3]);
      uint2 v = make_uint2(cvt_pk_bf16(t0, t1), cvt_pk_bf16(t2, t3));
      *(uint2*)&lds_h[m * 256 + ((cbase ^ (m & 7)) << 3) + off] = v;
    }
  }
}

__global__ __launch_bounds__(256, 4) void fbpinn_main(
    const float* __restrict__ x,  const float* __restrict__ W0, const float* __restrict__ b0,
    const float* __restrict__ b1, const float* __restrict__ b2,
    const float* __restrict__ W3, const float* __restrict__ b3,
    const float* __restrict__ xmins, const float* __restrict__ xmaxs,
    const short* __restrict__ wsw, const int* __restrict__ counts,
    const int* __restrict__ ilist, const float* __restrict__ wlist,
    float* __restrict__ out)
{
  __shared__ short lds_h[64 * 256];   // 32 KB, swizzled bf16 h tile, [m][j]
  __shared__ float s_xn[64 * 2];
  __shared__ float s_win[64];
  __shared__ int   s_pidx[64];
  __shared__ float s_w3[256];
  __shared__ float s_w0[512];

  const int t    = threadIdx.x;
  const int lane = t & 63;
  const int wave = t >> 6;
  const int col  = lane & 15;
  const int quad = lane >> 4;

  // live-tile partition: prefix over per-k tile counts
  int tb[17]; tb[0] = 0;
  #pragma unroll
  for (int kk = 0; kk < 16; kk++) tb[kk + 1] = tb[kk] + ((CNT(kk) + 63) >> 6);
  const int total = tb[16];

  // XCD-chunked tile mapping (T1): tiles are k-major; give each XCD a
  // CONTIGUOUS chunk so its private 4MB L2 only sees ~2 k's weight panels
  // (~0.5MB) instead of all 16 (4.2MB, thrash -> 8x HBM re-fetch).
  const int xcd   = blockIdx.x & 7;
  const int nb    = gridDim.x >> 3;        // blocks per xcd
  const int chunk = (total + 7) >> 3;      // tiles per xcd

  for (int idx = blockIdx.x >> 3; idx < chunk; idx += nb){
    const int tile = xcd * chunk + idx;
    if (tile >= total) break;
    int k = 0;
    #pragma unroll
    for (int kk = 1; kk < 16; kk++) k += (tile >= tb[kk]);
    const int base = (tile - tb[k]) * 64;
    const int cnt  = CNT(k);

    __syncthreads();   // previous tile's layer-3 reads done before s_* overwrite

    // ---- stage: gather compacted points, normalize, stage W0/W3 ----
    s_w3[t] = W3[k * 256 + t];
    s_w0[t] = W0[k * 512 + t];
    s_w0[256 + t] = W0[k * 512 + 256 + t];
    if (t < 64){
      int gi = base + t;
      bool valid = gi < cnt;
      int pidx = valid ? ilist[k * NPTS + gi] : 0;
      float w  = valid ? wlist[k * NPTS + gi] : 0.f;
      s_pidx[t] = pidx;
      s_win[t]  = w;
      float px = x[pidx * 2 + 0], py = x[pidx * 2 + 1];
      float cx = (xmins[k * 2 + 0] + xmaxs[k * 2 + 0]) * 0.5f;
      float cy = (xmins[k * 2 + 1] + xmaxs[k * 2 + 1]) * 0.5f;
      float sx = fmaxf((xmaxs[k * 2 + 0] - xmins[k * 2 + 0]) * 0.5f, 1e-9f);
      float sy = fmaxf((xmaxs[k * 2 + 1] - xmins[k * 2 + 1]) * 0.5f, 1e-9f);
      s_xn[t * 2 + 0] = (px - cx) / sx;
      s_xn[t * 2 + 1] = (py - cy) / sy;
    }
    __syncthreads();

    // ---- layer 0 (D=2 -> 256), swapped roles: D[j'][m] = W0^T(j',d) * xn^T(d,m) ----
    {
      short8 wfr[4], xfr[4];
      #pragma unroll
      for (int rt = 0; rt < 4; rt++){
        int j = (wave * 4 + rt) * 16 + col;        // A row = out-feature j'
        short8 a;
        #pragma unroll
        for (int i = 0; i < 8; i++) a[i] = 0;
        a[0] = (quad == 0) ? f2bf(s_w0[j])       : (short)0;
        a[1] = (quad == 0) ? f2bf(s_w0[256 + j]) : (short)0;
        wfr[rt] = a;
      }
      #pragma unroll
      for (int ct = 0; ct < 4; ct++){
        int m = ct * 16 + col;                     // B col = point m
        short8 b;
        #pragma unroll
        for (int i = 0; i < 8; i++) b[i] = 0;
        b[0] = (quad == 0) ? f2bf(s_xn[m * 2 + 0]) : (short)0;
        b[1] = (quad == 0) ? f2bf(s_xn[m * 2 + 1]) : (short)0;
        xfr[ct] = b;
      }
      floatx4 bb[4];
      #pragma unroll
      for (int rt = 0; rt < 4; rt++)
        bb[rt] = *(const floatx4*)&b0[k * 256 + (wave * 4 + rt) * 16 + quad * 4];
      floatx4 acc[4][4];
      #pragma unroll
      for (int a = 0; a < 4; a++)
        #pragma unroll
        for (int b = 0; b < 4; b++)
          acc[a][b] = (floatx4){0.f, 0.f, 0.f, 0.f};
      #pragma unroll
      for (int rt = 0; rt < 4; rt++)
        #pragma unroll
        for (int ct = 0; ct < 4; ct++)
          acc[rt][ct] = __builtin_amdgcn_mfma_f32_16x16x32_bf16(wfr[rt], xfr[ct], acc[rt][ct], 0, 0, 0);
      store_h_packed(lds_h, acc, bb, wave, quad, col);
      __syncthreads();
    }

    // ---- layers 1,2: D[j'][m] = W^T * h^T; weights = A (global), h = B (LDS) ----
    #pragma unroll 1
    for (int layer = 0; layer < 2; layer++){
      const short8* wb = (const short8*)(wsw + (size_t)layer * 1048576)
                         + ((size_t)(k * 8) * 16 + wave * 4) * 64 + lane;
      const float*  bp = layer ? b2 : b1;
      floatx4 bb[4];
      #pragma unroll
      for (int rt = 0; rt < 4; rt++)
        bb[rt] = *(const floatx4*)&bp[k * 256 + (wave * 4 + rt) * 16 + quad * 4];
      floatx4 acc[4][4];
      #pragma unroll
      for (int a = 0; a < 4; a++)
        #pragma unroll
        for (int b = 0; b < 4; b++)
          acc[a][b] = (floatx4){0.f, 0.f, 0.f, 0.f};

      short8 wcur[4];
      #pragma unroll
      for (int rt = 0; rt < 4; rt++) wcur[rt] = wb[rt * 64];

      #pragma unroll
      for (int ks = 0; ks < 8; ks++){
        short8 wnxt[4];
        if (ks < 7){
          #pragma unroll
          for (int rt = 0; rt < 4; rt++)
            wnxt[rt] = wb[(ks + 1) * 1024 + rt * 64];   // prefetch next K-step
        }
        short8 hfr[4];
        #pragma unroll
        for (int ct = 0; ct < 4; ct++){
          int m   = ct * 16 + col;                 // B: col = point m
          int pos = (ks * 4 + quad) ^ (m & 7);     // B: k-chunk = quad
          hfr[ct] = *(const short8*)&lds_h[m * 256 + pos * 8];
        }
        #pragma unroll
        for (int rt = 0; rt < 4; rt++)
          #pragma unroll
          for (int ct = 0; ct < 4; ct++)
            acc[rt][ct] = __builtin_amdgcn_mfma_f32_16x16x32_bf16(wcur[rt], hfr[ct], acc[rt][ct], 0, 0, 0);
        if (ks < 7){
          #pragma unroll
          for (int rt = 0; rt < 4; rt++) wcur[rt] = wnxt[rt];
        }
      }
      __syncthreads();   // all reads of h done before overwrite

      store_h_packed(lds_h, acc, bb, wave, quad, col);
      __syncthreads();
    }

    // ---- layer 3 (256 -> 1) + window-weighted scatter ----
    {
      int m = t >> 2, q = t & 3;     // 4 threads per point
      float dot = 0.f;
      #pragma unroll
      for (int cc = 0; cc < 8; cc++){
        int ci  = q * 8 + cc;
        int pos = ci ^ (m & 7);
        short8 hv = *(const short8*)&lds_h[m * 256 + pos * 8];
        #pragma unroll
        for (int jj = 0; jj < 8; jj++)
          dot = fmaf(bf2f(hv[jj]), s_w3[ci * 8 + jj], dot);
      }
      dot += __shfl_xor(dot, 1);
      dot += __shfl_xor(dot, 2);
      if (q == 0 && s_win[m] != 0.f)
        atomicAdd(&out[s_pidx[m]], s_win[m] * (dot + b3[k]));
    }
  }
}

extern "C" void kernel_launch(void* const* d_in, const int* in_sizes, int n_in,
                              void* d_out, int out_size, void* d_ws, size_t ws_size,
                              hipStream_t stream){
  const float* x     = (const float*)d_in[0];
  const float* W0    = (const float*)d_in[1];
  const float* b0    = (const float*)d_in[2];
  const float* W1    = (const float*)d_in[3];
  const float* b1    = (const float*)d_in[4];
  const float* W2    = (const float*)d_in[5];
  const float* b2    = (const float*)d_in[6];
  const float* W3    = (const float*)d_in[7];
  const float* b3    = (const float*)d_in[8];
  const float* xmins = (const float*)d_in[9];
  const float* xmaxs = (const float*)d_in[10];
  float* out = (float*)d_out;

  char* ws = (char*)d_ws;                     // needs ~6.3 MB
  short* wsw   = (short*)(ws + WS_W);
  int*   cnts  = (int*)  (ws + WS_CNT);
  int*   ilist = (int*)  (ws + WS_ILIST);
  float* wlist = (float*)(ws + WS_WLIST);

  (void)hipMemsetAsync(cnts, 0, 4096, stream);
  prep_fused<<<1024 + 256, 256, 0, stream>>>(W1, W2, x, xmins, xmaxs,
                                             wsw, cnts, ilist, wlist, out);
  // grid 2048 = 8 XCDs x 256 blocks; fbpinn_main chunks the k-major tile
  // list per-XCD for L2 locality (see kernel comment).
  fbpinn_main<<<2048, 256, 0, stream>>>(x, W0, b0, b1, b2, W3, b3, xmins, xmaxs,
                                        wsw, cnts, ilist, wlist, out);
}